// Round 2
// baseline (1563.781 us; speedup 1.0000x reference)
//
#include <hip/hip_runtime.h>
#include <hip/hip_bf16.h>
#include <stdint.h>
#include <stddef.h>

#define NSP 110592      // 48^3
#define SD  48
#define SD2 2304        // 48*48
#define CIN 128
#define C3  384
#define NH  8
#define NB  2
#define NQ  84934656ull // NB*C3*NSP

typedef __hip_bfloat16 bf16;
typedef __bf16 bf16x8 __attribute__((ext_vector_type(8)));
typedef float  f32x4  __attribute__((ext_vector_type(4)));

// wbuf element offsets (all bf16): qkvw | dww | projw | temp
#define WOFF_QKVW 0
#define WOFF_DWW  49152
#define WOFF_PROJ 59520
#define WOFF_TEMP 75904
#define WTOTAL    75912

__device__ __forceinline__ float ldb(const bf16* p){ return __bfloat162float(*p); }

// ---- sniffer: flag=1 if inputs are fp32, 0 if bf16 ---------------------------
__global__ void k_sniff(const uint16_t* __restrict__ x16, int* __restrict__ flag)
{
    int t = threadIdx.x; int cnt = 0;
    for (int i = 0; i < 16; ++i) {
        uint16_t b = x16[(size_t)(t * 16 + i) * 2];   // even halves only
        int e = (b >> 7) & 0xFF;
        if (e >= 100 && e <= 140) ++cnt;              // bf16-exponent-plausible
    }
    for (int off = 32; off; off >>= 1) cnt += __shfl_down(cnt, off, 64);
    __shared__ int s[4];
    if ((t & 63) == 0) s[t >> 6] = cnt;
    __syncthreads();
    if (t == 0) *flag = (s[0] + s[1] + s[2] + s[3] < 2048) ? 1 : 0;
}

// ---- canonicalize all weights to bf16 in wbuf --------------------------------
__global__ void k_cvtw(const void* __restrict__ qw, const void* __restrict__ dw,
                       const void* __restrict__ pw, const void* __restrict__ tw,
                       bf16* __restrict__ wbuf, const int* __restrict__ flagp)
{
    int f = *flagp;
    int idx = blockIdx.x * 256 + threadIdx.x;
    if (idx >= WTOTAL) return;
    const void* src; int off;
    if (idx < WOFF_DWW)      { src = qw; off = idx; }
    else if (idx < WOFF_PROJ){ src = dw; off = idx - WOFF_DWW; }
    else if (idx < WOFF_TEMP){ src = pw; off = idx - WOFF_PROJ; }
    else                     { src = tw; off = idx - WOFF_TEMP; }
    float v = f ? ((const float*)src)[off]
                : __bfloat162float(((const bf16*)src)[off]);
    wbuf[idx] = __float2bfloat16(v);
}

// ---- K0: transpose x[b][c][n] -> xT[b][n][c] (bf16 out, dual-dtype in) -------
__global__ __launch_bounds__(256) void k_transpose(const void* __restrict__ xin,
                                                   bf16* __restrict__ xT,
                                                   const int* __restrict__ flagp)
{
    int f = *flagp;
    int b = blockIdx.y;
    size_t tid = (size_t)blockIdx.x * 256 + threadIdx.x;
    int c = (int)(tid & 127);
    size_t n8 = tid >> 7;
    size_t base = ((size_t)b * CIN + c) * NSP + n8 * 8;
    bf16 pv[8];
    if (f) {
        const float* src = (const float*)xin + base;
        float4 a = *(const float4*)src;
        float4 d = *(const float4*)(src + 4);
        pv[0] = __float2bfloat16(a.x); pv[1] = __float2bfloat16(a.y);
        pv[2] = __float2bfloat16(a.z); pv[3] = __float2bfloat16(a.w);
        pv[4] = __float2bfloat16(d.x); pv[5] = __float2bfloat16(d.y);
        pv[6] = __float2bfloat16(d.z); pv[7] = __float2bfloat16(d.w);
    } else {
        uint4 v = *(const uint4*)((const bf16*)xin + base);
        const bf16* q = (const bf16*)&v;
#pragma unroll
        for (int j = 0; j < 8; ++j) pv[j] = q[j];
    }
    bf16* dst = xT + ((size_t)b * NSP + n8 * 8) * CIN + c;
#pragma unroll
    for (int j = 0; j < 8; ++j) dst[(size_t)j * CIN] = pv[j];
}

// ---- GEMM  C[b][m][n] = A[m][k] * BT[b][n][k], K=128, 128x128 tiles ----------
// flagp==nullptr -> bf16 out; else *flagp==1 -> fp32 out, 0 -> bf16 out.
__global__ __launch_bounds__(256) void k_gemm_bt(const bf16* __restrict__ A,
                                                 const bf16* __restrict__ BT,
                                                 void* __restrict__ Cout,
                                                 int Mtotal,
                                                 const int* __restrict__ flagp)
{
    __shared__ __align__(16) bf16 lA[128 * CIN];
    __shared__ __align__(16) bf16 lB[128 * CIN];
    int b = blockIdx.z, mb = blockIdx.y;
    size_t nbase = (size_t)blockIdx.x * 128;
    const bf16* gA = A + (size_t)mb * 128 * CIN;
    const bf16* gB = BT + ((size_t)b * NSP + nbase) * CIN;
    int t = threadIdx.x;
#pragma unroll
    for (int i = 0; i < 8; ++i) {
        int off = (i * 256 + t) * 8;
        *(uint4*)&lA[off] = *(const uint4*)&gA[off];
        *(uint4*)&lB[off] = *(const uint4*)&gB[off];
    }
    __syncthreads();

    int wave = t >> 6, lane = t & 63;
    int wm = (wave & 1) * 64, wn = (wave >> 1) * 64;
    int lr = lane & 15, lq = lane >> 4;
    f32x4 acc[4][4];
#pragma unroll
    for (int mi = 0; mi < 4; ++mi)
#pragma unroll
        for (int ni = 0; ni < 4; ++ni) acc[mi][ni] = (f32x4){0.f, 0.f, 0.f, 0.f};

#pragma unroll
    for (int ks = 0; ks < 4; ++ks) {
        int kof = ks * 32 + lq * 8;
        bf16x8 af[4], bfv[4];
#pragma unroll
        for (int mi = 0; mi < 4; ++mi)
            af[mi] = *(const bf16x8*)&lA[(wm + mi * 16 + lr) * CIN + kof];
#pragma unroll
        for (int ni = 0; ni < 4; ++ni)
            bfv[ni] = *(const bf16x8*)&lB[(wn + ni * 16 + lr) * CIN + kof];
#pragma unroll
        for (int mi = 0; mi < 4; ++mi)
#pragma unroll
            for (int ni = 0; ni < 4; ++ni)
                acc[mi][ni] = __builtin_amdgcn_mfma_f32_16x16x32_bf16(
                    af[mi], bfv[ni], acc[mi][ni], 0, 0, 0);
    }

    int f32o = flagp ? *flagp : 0;
    size_t cb = ((size_t)b * Mtotal + (size_t)mb * 128) * NSP + nbase;
    if (f32o) {
        float* Cb = (float*)Cout + cb;
#pragma unroll
        for (int mi = 0; mi < 4; ++mi)
#pragma unroll
            for (int ni = 0; ni < 4; ++ni)
#pragma unroll
                for (int r = 0; r < 4; ++r)
                    Cb[(size_t)(wm + mi * 16 + lq * 4 + r) * NSP + wn + ni * 16 + lr]
                        = acc[mi][ni][r];
    } else {
        bf16* Cb = (bf16*)Cout + cb;
#pragma unroll
        for (int mi = 0; mi < 4; ++mi)
#pragma unroll
            for (int ni = 0; ni < 4; ++ni)
#pragma unroll
                for (int r = 0; r < 4; ++r)
                    Cb[(size_t)(wm + mi * 16 + lq * 4 + r) * NSP + wn + ni * 16 + lr]
                        = __float2bfloat16(acc[mi][ni][r]);
    }
}

// ---- K2: depthwise 3x3x3 conv (bf16->bf16) + per-channel sum of squares ------
__device__ __forceinline__ void loadplane(const bf16* src, int zp, int y, int d,
                                          float p[3][3])
{
    bool zin = (unsigned)zp < SD;
    const bf16* pz = src + (size_t)zp * SD2;
#pragma unroll
    for (int dy = 0; dy < 3; ++dy) {
        int yy = y + dy - 1;
#pragma unroll
        for (int dd = 0; dd < 3; ++dd) {
            int xx = d + dd - 1;
            float v = 0.f;
            if (zin && (unsigned)yy < SD && (unsigned)xx < SD) v = ldb(&pz[yy * SD + xx]);
            p[dy][dd] = v;
        }
    }
}

__global__ __launch_bounds__(256) void k_dwconv(const bf16* __restrict__ qkv1,
                                                const bf16* __restrict__ dw,
                                                bf16* __restrict__ qkv2,
                                                float* __restrict__ sums)
{
    int bc = blockIdx.x;
    int ch = bc % C3;
    const bf16* src = qkv1 + (size_t)bc * NSP;
    bf16* dst = qkv2 + (size_t)bc * NSP;
    float wgt[27];
#pragma unroll
    for (int i = 0; i < 27; ++i) wgt[i] = __bfloat162float(dw[ch * 27 + i]);
    int t = threadIdx.x;
    float ssq = 0.f;
    for (int chunk = 0; chunk < 9; ++chunk) {
        int flat = chunk * 256 + t;
        int y = flat / SD;
        int d = flat - y * SD;
        float pl[3][3][3];
#pragma unroll
        for (int a = 0; a < 3; ++a)
#pragma unroll
            for (int e = 0; e < 3; ++e) pl[0][a][e] = 0.f;
        loadplane(src, 0, y, d, pl[1]);
        loadplane(src, 1, y, d, pl[2]);
        for (int z = 0; z < SD; ++z) {
            float acc = 0.f;
#pragma unroll
            for (int zi = 0; zi < 3; ++zi)
#pragma unroll
                for (int dy = 0; dy < 3; ++dy)
#pragma unroll
                    for (int dd = 0; dd < 3; ++dd)
                        acc += wgt[zi * 9 + dy * 3 + dd] * pl[zi][dy][dd];
            dst[(size_t)z * SD2 + flat] = __float2bfloat16(acc);
            ssq += acc * acc;
#pragma unroll
            for (int a = 0; a < 3; ++a)
#pragma unroll
                for (int e = 0; e < 3; ++e) {
                    pl[0][a][e] = pl[1][a][e];
                    pl[1][a][e] = pl[2][a][e];
                }
            loadplane(src, z + 2, y, d, pl[2]);
        }
    }
    for (int off = 32; off; off >>= 1) ssq += __shfl_down(ssq, off, 64);
    __shared__ float red[4];
    if ((t & 63) == 0) red[t >> 6] = ssq;
    __syncthreads();
    if (t == 0) sums[bc] = red[0] + red[1] + red[2] + red[3];
}

// ---- K3: raw scores S[b][h][i][j] = sum_n q_i k_j ----------------------------
__global__ __launch_bounds__(256) void k_scores(const bf16* __restrict__ qkv2,
                                                float* __restrict__ scores)
{
    int b = blockIdx.z, h = blockIdx.y;
    const bf16* qb = qkv2 + ((size_t)b * C3 + h * 16) * NSP;
    const bf16* kb = qkv2 + ((size_t)b * C3 + 128 + h * 16) * NSP;
    int t = threadIdx.x;
    int ig = t >> 6;
    float acc[4][16];
#pragma unroll
    for (int i = 0; i < 4; ++i)
#pragma unroll
        for (int j = 0; j < 16; ++j) acc[i][j] = 0.f;
    size_t nb = (size_t)blockIdx.x * 4096;
    for (int ii = 0; ii < 16; ++ii) {
        size_t n = nb + (size_t)ii * 256 + t;
        float qv[4], kv[16];
#pragma unroll
        for (int j = 0; j < 16; ++j) kv[j] = ldb(&kb[(size_t)j * NSP + n]);
#pragma unroll
        for (int i = 0; i < 4; ++i) qv[i] = ldb(&qb[(size_t)(ig * 4 + i) * NSP + n]);
#pragma unroll
        for (int i = 0; i < 4; ++i)
#pragma unroll
            for (int j = 0; j < 16; ++j) acc[i][j] += qv[i] * kv[j];
    }
    float* srow = scores + (size_t)(b * NH + h) * 256;
#pragma unroll
    for (int i = 0; i < 4; ++i)
#pragma unroll
        for (int j = 0; j < 16; ++j) {
            float v = acc[i][j];
            for (int off = 32; off; off >>= 1) v += __shfl_down(v, off, 64);
            if ((t & 63) == 0) atomicAdd(&srow[(ig * 4 + i) * 16 + j], v);
        }
}

// ---- K4: normalize + temperature + softmax -----------------------------------
__global__ void k_softmax(const float* __restrict__ scores,
                          const float* __restrict__ sums,
                          const bf16* __restrict__ temp,
                          float* __restrict__ attn)
{
    int t = threadIdx.x;             // t = b*128 + h*16 + i
    int h = (t >> 4) & 7, b = t >> 7;
    float tau = __bfloat162float(temp[h]);
    float invq = 1.f / fmaxf(sqrtf(sums[b * C3 + (t & 127)]), 1e-12f);
    const float* srow = scores + (size_t)t * 16;
    float s[16]; float mx = -3.4e38f;
#pragma unroll
    for (int j = 0; j < 16; ++j) {
        float invk = 1.f / fmaxf(sqrtf(sums[b * C3 + 128 + h * 16 + j]), 1e-12f);
        s[j] = srow[j] * invq * invk * tau;
        mx = fmaxf(mx, s[j]);
    }
    float sum = 0.f;
#pragma unroll
    for (int j = 0; j < 16; ++j) { s[j] = expf(s[j] - mx); sum += s[j]; }
    float inv = 1.f / sum;
    float* arow = attn + (size_t)t * 16;
#pragma unroll
    for (int j = 0; j < 16; ++j) arow[j] = s[j] * inv;
}

// ---- K5: outT[b][n][h*16+i] = sum_j attn[i][j] v[j][n] -----------------------
__global__ __launch_bounds__(256) void k_av(const bf16* __restrict__ qkv2,
                                            const float* __restrict__ attn,
                                            bf16* __restrict__ outT)
{
    int b = blockIdx.z, h = blockIdx.y;
    const bf16* vb = qkv2 + ((size_t)b * C3 + 256 + h * 16) * NSP;
    __shared__ float at[256];
    int t = threadIdx.x;
    {
        int i = t >> 4, j = t & 15;
        at[j * 16 + i] = attn[(size_t)(b * NH + h) * 256 + t];
    }
    __syncthreads();
    int i = t & 15, nof = t >> 4;
    size_t nb = (size_t)blockIdx.x * 2048;
    bf16* ob = outT + (size_t)b * NSP * CIN + h * 16 + i;
    for (int ii = 0; ii < 128; ++ii) {
        size_t n = nb + (size_t)ii * 16 + nof;
        float o = 0.f;
#pragma unroll
        for (int j = 0; j < 16; ++j) o += at[j * 16 + i] * ldb(&vb[(size_t)j * NSP + n]);
        ob[n * CIN] = __float2bfloat16(o);
    }
}

// ---- host --------------------------------------------------------------------
extern "C" void kernel_launch(void* const* d_in, const int* in_sizes, int n_in,
                              void* d_out, int out_size, void* d_ws, size_t ws_size,
                              hipStream_t stream)
{
    // identify inputs by element count (robust to ordering)
    const void *px = nullptr, *pq = nullptr, *pd = nullptr, *pp = nullptr, *pt = nullptr;
    for (int i = 0; i < n_in; ++i) {
        switch (in_sizes[i]) {
            case 28311552: px = d_in[i]; break;   // x
            case 49152:    pq = d_in[i]; break;   // qkv_w
            case 10368:    pd = d_in[i]; break;   // dw_w
            case 16384:    pp = d_in[i]; break;   // proj_w
            case 8:        pt = d_in[i]; break;   // temperature
        }
    }
    const size_t required = NQ * 4 + (1u << 20);
    if (!px || !pq || !pd || !pp || !pt || ws_size < required) {
        // graceful, recognizable failure: zero output (absmax == max|ref|)
        (void)hipMemsetAsync(d_out, 0, (size_t)out_size * 2, stream);
        return;
    }

    char* ws = (char*)d_ws;
    bf16* qkv1 = (bf16*)ws;                       // NQ bf16
    bf16* qkv2 = (bf16*)(ws + NQ * 2);            // NQ bf16
    char* small = ws + NQ * 4;
    int*   flag   = (int*)small;
    float* sums   = (float*)(small + 256);
    float* scores = (float*)(small + 8192);
    float* attn   = (float*)(small + 24576);
    bf16*  wbuf   = (bf16*)(small + 40960);
    bf16* xT   = qkv2;   // alias: dead before k_dwconv writes qkv2
    bf16* outT = qkv1;   // alias: qkv1 dead after k_dwconv

    (void)hipMemsetAsync(scores, 0, 4096 * sizeof(float), stream);
    k_sniff<<<1, 256, 0, stream>>>((const uint16_t*)px, flag);
    k_cvtw<<<(WTOTAL + 255) / 256, 256, 0, stream>>>(pq, pd, pp, pt, wbuf, flag);
    k_transpose<<<dim3(6912, NB), 256, 0, stream>>>(px, xT, flag);
    k_gemm_bt<<<dim3(NSP / 128, 3, NB), 256, 0, stream>>>(
        wbuf + WOFF_QKVW, xT, qkv1, C3, nullptr);
    k_dwconv<<<dim3(NB * C3), 256, 0, stream>>>(qkv1, wbuf + WOFF_DWW, qkv2, sums);
    k_scores<<<dim3(27, NH, NB), 256, 0, stream>>>(qkv2, scores);
    k_softmax<<<1, 256, 0, stream>>>(scores, sums, wbuf + WOFF_TEMP, attn);
    k_av<<<dim3(NSP / 2048, NH, NB), 256, 0, stream>>>(qkv2, attn, outT);
    k_gemm_bt<<<dim3(NSP / 128, 1, NB), 256, 0, stream>>>(
        wbuf + WOFF_PROJ, outT, d_out, CIN, flag);
}

// Round 3
// 807.320 us; speedup vs baseline: 1.9370x; 1.9370x over previous
//
#include <hip/hip_runtime.h>
#include <hip/hip_bf16.h>
#include <stdint.h>
#include <stddef.h>

#define NSP 110592      // 48^3
#define SD  48
#define SD2 2304        // 48*48
#define CIN 128
#define C3  384
#define NH  8
#define NB  2
#define NQ  84934656ull // NB*C3*NSP

typedef __hip_bfloat16 bf16;
typedef __bf16 bf16x8 __attribute__((ext_vector_type(8)));
typedef float  f32x4  __attribute__((ext_vector_type(4)));

// wbuf element offsets (all bf16): qkvw | dww | projw | temp
#define WOFF_QKVW 0
#define WOFF_DWW  49152
#define WOFF_PROJ 59520
#define WOFF_TEMP 75904
#define WTOTAL    75912

__device__ __forceinline__ float ldb(const bf16* p){ return __bfloat162float(*p); }

// ---- sniffer: flag=1 if inputs are fp32, 0 if bf16 ---------------------------
__global__ void k_sniff(const uint16_t* __restrict__ x16, int* __restrict__ flag)
{
    int t = threadIdx.x; int cnt = 0;
    for (int i = 0; i < 16; ++i) {
        uint16_t b = x16[(size_t)(t * 16 + i) * 2];   // even halves only
        int e = (b >> 7) & 0xFF;
        if (e >= 100 && e <= 140) ++cnt;              // bf16-exponent-plausible
    }
    for (int off = 32; off; off >>= 1) cnt += __shfl_down(cnt, off, 64);
    __shared__ int s[4];
    if ((t & 63) == 0) s[t >> 6] = cnt;
    __syncthreads();
    if (t == 0) *flag = (s[0] + s[1] + s[2] + s[3] < 2048) ? 1 : 0;
}

// ---- canonicalize all weights to bf16 in wbuf --------------------------------
__global__ void k_cvtw(const void* __restrict__ qw, const void* __restrict__ dw,
                       const void* __restrict__ pw, const void* __restrict__ tw,
                       bf16* __restrict__ wbuf, const int* __restrict__ flagp)
{
    int f = *flagp;
    int idx = blockIdx.x * 256 + threadIdx.x;
    if (idx >= WTOTAL) return;
    const void* src; int off;
    if (idx < WOFF_DWW)      { src = qw; off = idx; }
    else if (idx < WOFF_PROJ){ src = dw; off = idx - WOFF_DWW; }
    else if (idx < WOFF_TEMP){ src = pw; off = idx - WOFF_PROJ; }
    else                     { src = tw; off = idx - WOFF_TEMP; }
    float v = f ? ((const float*)src)[off]
                : __bfloat162float(((const bf16*)src)[off]);
    wbuf[idx] = __float2bfloat16(v);
}

// ---- K0: transpose x[b][c][n] -> xT[b][n][c] (bf16 out, dual-dtype in) -------
__global__ __launch_bounds__(256) void k_transpose(const void* __restrict__ xin,
                                                   bf16* __restrict__ xT,
                                                   const int* __restrict__ flagp)
{
    int f = *flagp;
    int b = blockIdx.y;
    size_t tid = (size_t)blockIdx.x * 256 + threadIdx.x;
    int c = (int)(tid & 127);
    size_t n8 = tid >> 7;
    size_t base = ((size_t)b * CIN + c) * NSP + n8 * 8;
    bf16 pv[8];
    if (f) {
        const float* src = (const float*)xin + base;
        float4 a = *(const float4*)src;
        float4 d = *(const float4*)(src + 4);
        pv[0] = __float2bfloat16(a.x); pv[1] = __float2bfloat16(a.y);
        pv[2] = __float2bfloat16(a.z); pv[3] = __float2bfloat16(a.w);
        pv[4] = __float2bfloat16(d.x); pv[5] = __float2bfloat16(d.y);
        pv[6] = __float2bfloat16(d.z); pv[7] = __float2bfloat16(d.w);
    } else {
        uint4 v = *(const uint4*)((const bf16*)xin + base);
        const bf16* q = (const bf16*)&v;
#pragma unroll
        for (int j = 0; j < 8; ++j) pv[j] = q[j];
    }
    bf16* dst = xT + ((size_t)b * NSP + n8 * 8) * CIN + c;
#pragma unroll
    for (int j = 0; j < 8; ++j) dst[(size_t)j * CIN] = pv[j];
}

// ---- GEMM  C[b][m][n] = A[m][k] * BT[b][n][k], K=128, 128x128 tiles ----------
__global__ __launch_bounds__(256) void k_gemm_bt(const bf16* __restrict__ A,
                                                 const bf16* __restrict__ BT,
                                                 void* __restrict__ Cout,
                                                 int Mtotal,
                                                 const int* __restrict__ flagp)
{
    __shared__ __align__(16) bf16 lA[128 * CIN];
    __shared__ __align__(16) bf16 lB[128 * CIN];
    int b = blockIdx.z, mb = blockIdx.y;
    size_t nbase = (size_t)blockIdx.x * 128;
    const bf16* gA = A + (size_t)mb * 128 * CIN;
    const bf16* gB = BT + ((size_t)b * NSP + nbase) * CIN;
    int t = threadIdx.x;
#pragma unroll
    for (int i = 0; i < 8; ++i) {
        int off = (i * 256 + t) * 8;
        *(uint4*)&lA[off] = *(const uint4*)&gA[off];
        *(uint4*)&lB[off] = *(const uint4*)&gB[off];
    }
    __syncthreads();

    int wave = t >> 6, lane = t & 63;
    int wm = (wave & 1) * 64, wn = (wave >> 1) * 64;
    int lr = lane & 15, lq = lane >> 4;
    f32x4 acc[4][4];
#pragma unroll
    for (int mi = 0; mi < 4; ++mi)
#pragma unroll
        for (int ni = 0; ni < 4; ++ni) acc[mi][ni] = (f32x4){0.f, 0.f, 0.f, 0.f};

#pragma unroll
    for (int ks = 0; ks < 4; ++ks) {
        int kof = ks * 32 + lq * 8;
        bf16x8 af[4], bfv[4];
#pragma unroll
        for (int mi = 0; mi < 4; ++mi)
            af[mi] = *(const bf16x8*)&lA[(wm + mi * 16 + lr) * CIN + kof];
#pragma unroll
        for (int ni = 0; ni < 4; ++ni)
            bfv[ni] = *(const bf16x8*)&lB[(wn + ni * 16 + lr) * CIN + kof];
#pragma unroll
        for (int mi = 0; mi < 4; ++mi)
#pragma unroll
            for (int ni = 0; ni < 4; ++ni)
                acc[mi][ni] = __builtin_amdgcn_mfma_f32_16x16x32_bf16(
                    af[mi], bfv[ni], acc[mi][ni], 0, 0, 0);
    }

    int f32o = flagp ? *flagp : 0;
    size_t cb = ((size_t)b * Mtotal + (size_t)mb * 128) * NSP + nbase;
    if (f32o) {
        float* Cb = (float*)Cout + cb;
#pragma unroll
        for (int mi = 0; mi < 4; ++mi)
#pragma unroll
            for (int ni = 0; ni < 4; ++ni)
#pragma unroll
                for (int r = 0; r < 4; ++r)
                    Cb[(size_t)(wm + mi * 16 + lq * 4 + r) * NSP + wn + ni * 16 + lr]
                        = acc[mi][ni][r];
    } else {
        bf16* Cb = (bf16*)Cout + cb;
#pragma unroll
        for (int mi = 0; mi < 4; ++mi)
#pragma unroll
            for (int ni = 0; ni < 4; ++ni)
#pragma unroll
                for (int r = 0; r < 4; ++r)
                    Cb[(size_t)(wm + mi * 16 + lq * 4 + r) * NSP + wn + ni * 16 + lr]
                        = __float2bfloat16(acc[mi][ni][r]);
    }
}

// ---- K2: depthwise 3x3x3 conv, LDS-tiled, zero-haloed planes -----------------
// grid: (bc=768, slab=8); block: 256 threads; slab covers 6 output z-planes.
// LDS: 8 input planes (z0-1..z0+6), each 50 rows x 64 cols (halo at col 7 & 56,
// interior cols 8..55), bf16. Plane stride 3200 elems. 51200 B -> 3 blocks/CU.
#define PLN 3200        // 64*50
__global__ __launch_bounds__(256) void k_dwconv(const bf16* __restrict__ qkv1,
                                                const bf16* __restrict__ dw,
                                                bf16* __restrict__ qkv2,
                                                float* __restrict__ sums)
{
    __shared__ __align__(16) bf16 lds[8 * PLN];
    __shared__ float red[4];
    int bc = blockIdx.x;
    int slab = blockIdx.y;
    int z0 = slab * 6;
    int ch = bc % C3;
    int t = threadIdx.x;
    const bf16* src = qkv1 + (size_t)bc * NSP;
    bf16* dst = qkv2 + (size_t)bc * NSP;

    float wgt[27];
#pragma unroll
    for (int i = 0; i < 27; ++i) wgt[i] = ldb(&dw[ch * 27 + i]);

    // phase 0: zero all of LDS (8*3200 elems = 3200 uint4)
#pragma unroll
    for (int i = 0; i < 13; ++i) {
        int idx = i * 256 + t;
        if (idx < 3200) *(uint4*)&lds[idx * 8] = (uint4){0, 0, 0, 0};
    }
    __syncthreads();

    // phase 1: stage 8 planes (z0-1 .. z0+6); 288 uint4 per plane
#pragma unroll
    for (int i = 0; i < 9; ++i) {
        int vidx = i * 256 + t;            // 0..2303
        int p = vidx / 288;
        int r = vidx - p * 288;
        int y = r / 6;
        int dg = r - y * 6;
        int zp = z0 - 1 + p;
        if ((unsigned)zp < SD) {
            uint4 v = *(const uint4*)&src[(size_t)zp * SD2 + y * SD + dg * 8];
            *(uint4*)&lds[(p * PLN + (y + 1) * 64 + 8 + dg * 8)] = v;
        }
    }
    __syncthreads();

    // phase 2: compute. Each thread: 9 (y,d) columns, 6 z-outputs each.
    float ssq = 0.f;
#pragma unroll 1
    for (int c = 0; c < 9; ++c) {
        int flat = c * 256 + t;            // 0..2303
        int y = flat / SD;
        int d = flat - y * SD;
        int base = y * 64 + 7 + d;         // row y+dy -> (y+dy)*64; col 7+d+dd
        float acc[6] = {0.f, 0.f, 0.f, 0.f, 0.f, 0.f};
#pragma unroll
        for (int pl = 0; pl < 8; ++pl) {
            const bf16* P = &lds[pl * PLN + base];
            float v[9];
#pragma unroll
            for (int dy = 0; dy < 3; ++dy)
#pragma unroll
                for (int dd = 0; dd < 3; ++dd)
                    v[dy * 3 + dd] = ldb(&P[dy * 64 + dd]);
            float a0 = 0.f, a1 = 0.f, a2 = 0.f;
#pragma unroll
            for (int k = 0; k < 9; ++k) {
                a0 += wgt[k] * v[k];
                a1 += wgt[9 + k] * v[k];
                a2 += wgt[18 + k] * v[k];
            }
            if (pl <= 5) acc[pl] += a0;                    // zi=0 -> oz = pl
            if (pl >= 1 && pl <= 6) acc[pl - 1] += a1;     // zi=1 -> oz = pl-1
            if (pl >= 2) acc[pl - 2] += a2;                // zi=2 -> oz = pl-2
        }
#pragma unroll
        for (int oz = 0; oz < 6; ++oz) {
            dst[(size_t)(z0 + oz) * SD2 + flat] = __float2bfloat16(acc[oz]);
            ssq += acc[oz] * acc[oz];
        }
    }

    for (int off = 32; off; off >>= 1) ssq += __shfl_down(ssq, off, 64);
    if ((t & 63) == 0) red[t >> 6] = ssq;
    __syncthreads();
    if (t == 0) atomicAdd(&sums[bc], red[0] + red[1] + red[2] + red[3]);
}

// ---- K3: scores S[b][h][i][j] = sum_n q_i k_j  (MFMA, full n coverage) -------
// grid (108, NH, NB); wave w covers 256 contiguous n (8 chunks of 32).
__global__ __launch_bounds__(256) void k_scores(const bf16* __restrict__ qkv2,
                                                float* __restrict__ scores)
{
    int b = blockIdx.z, h = blockIdx.y;
    const bf16* qb = qkv2 + ((size_t)b * C3 + h * 16) * NSP;
    const bf16* kb = qkv2 + ((size_t)b * C3 + 128 + h * 16) * NSP;
    int t = threadIdx.x, w = t >> 6, lane = t & 63;
    int m = lane & 15, q4 = lane >> 4;
    size_t n0 = (size_t)blockIdx.x * 1024 + (size_t)w * 256 + (size_t)q4 * 8;
    const bf16* qp = qb + (size_t)m * NSP + n0;
    const bf16* kp = kb + (size_t)m * NSP + n0;
    f32x4 acc = (f32x4){0.f, 0.f, 0.f, 0.f};
#pragma unroll
    for (int it = 0; it < 8; ++it) {
        bf16x8 a  = *(const bf16x8*)(qp + it * 32);
        bf16x8 bb = *(const bf16x8*)(kp + it * 32);
        acc = __builtin_amdgcn_mfma_f32_16x16x32_bf16(a, bb, acc, 0, 0, 0);
    }
    float* srow = scores + (size_t)(b * NH + h) * 256;
#pragma unroll
    for (int r = 0; r < 4; ++r)
        atomicAdd(&srow[(q4 * 4 + r) * 16 + m], acc[r]);
}

// ---- K4: normalize + temperature + softmax -----------------------------------
__global__ void k_softmax(const float* __restrict__ scores,
                          const float* __restrict__ sums,
                          const bf16* __restrict__ temp,
                          float* __restrict__ attn)
{
    int t = threadIdx.x;             // t = b*128 + h*16 + i
    int h = (t >> 4) & 7, b = t >> 7;
    float tau = __bfloat162float(temp[h]);
    float invq = 1.f / fmaxf(sqrtf(sums[b * C3 + (t & 127)]), 1e-12f);
    const float* srow = scores + (size_t)t * 16;
    float s[16]; float mx = -3.4e38f;
#pragma unroll
    for (int j = 0; j < 16; ++j) {
        float invk = 1.f / fmaxf(sqrtf(sums[b * C3 + 128 + h * 16 + j]), 1e-12f);
        s[j] = srow[j] * invq * invk * tau;
        mx = fmaxf(mx, s[j]);
    }
    float sum = 0.f;
#pragma unroll
    for (int j = 0; j < 16; ++j) { s[j] = expf(s[j] - mx); sum += s[j]; }
    float inv = 1.f / sum;
    float* arow = attn + (size_t)t * 16;
#pragma unroll
    for (int j = 0; j < 16; ++j) arow[j] = s[j] * inv;
}

// ---- K5: outT[b][n][h*16+i] = sum_j attn[i][j] v[j][n] -----------------------
// grid (108, NH, NB); thread handles 4 contiguous n; full j-reduction in-thread.
__global__ __launch_bounds__(256) void k_av(const bf16* __restrict__ qkv2,
                                            const float* __restrict__ attn,
                                            bf16* __restrict__ outT)
{
    int b = blockIdx.z, h = blockIdx.y;
    const bf16* vb = qkv2 + ((size_t)b * C3 + 256 + h * 16) * NSP;
    __shared__ float at[256];        // at[j*16+i]
    int t = threadIdx.x;
    {
        int i = t >> 4, j = t & 15;
        at[j * 16 + i] = attn[(size_t)(b * NH + h) * 256 + t];
    }
    __syncthreads();
    size_t n0 = (size_t)blockIdx.x * 1024 + (size_t)t * 4;
    float acc[16][4];
#pragma unroll
    for (int i = 0; i < 16; ++i)
#pragma unroll
        for (int k = 0; k < 4; ++k) acc[i][k] = 0.f;
#pragma unroll
    for (int j = 0; j < 16; ++j) {
        uint2 raw = *(const uint2*)&vb[(size_t)j * NSP + n0];
        const bf16* rp = (const bf16*)&raw;
        float vf[4];
#pragma unroll
        for (int k = 0; k < 4; ++k) vf[k] = ldb(&rp[k]);
#pragma unroll
        for (int i = 0; i < 16; ++i) {
            float wv = at[j * 16 + i];
#pragma unroll
            for (int k = 0; k < 4; ++k) acc[i][k] += wv * vf[k];
        }
    }
    bf16* ob = outT + ((size_t)b * NSP + n0) * CIN + h * 16;
#pragma unroll
    for (int k = 0; k < 4; ++k) {
        bf16 tmp[16];
#pragma unroll
        for (int i = 0; i < 16; ++i) tmp[i] = __float2bfloat16(acc[i][k]);
        *(uint4*)&ob[(size_t)k * CIN]     = *(uint4*)&tmp[0];
        *(uint4*)&ob[(size_t)k * CIN + 8] = *(uint4*)&tmp[8];
    }
}

// ---- host --------------------------------------------------------------------
extern "C" void kernel_launch(void* const* d_in, const int* in_sizes, int n_in,
                              void* d_out, int out_size, void* d_ws, size_t ws_size,
                              hipStream_t stream)
{
    const void *px = nullptr, *pq = nullptr, *pd = nullptr, *pp = nullptr, *pt = nullptr;
    for (int i = 0; i < n_in; ++i) {
        switch (in_sizes[i]) {
            case 28311552: px = d_in[i]; break;   // x
            case 49152:    pq = d_in[i]; break;   // qkv_w
            case 10368:    pd = d_in[i]; break;   // dw_w
            case 16384:    pp = d_in[i]; break;   // proj_w
            case 8:        pt = d_in[i]; break;   // temperature
        }
    }
    const size_t required = NQ * 4 + (1u << 20);
    if (!px || !pq || !pd || !pp || !pt || ws_size < required) {
        (void)hipMemsetAsync(d_out, 0, (size_t)out_size * 2, stream);
        return;
    }

    char* ws = (char*)d_ws;
    bf16* qkv1 = (bf16*)ws;                       // NQ bf16
    bf16* qkv2 = (bf16*)(ws + NQ * 2);            // NQ bf16
    char* small = ws + NQ * 4;
    int*   flag   = (int*)small;
    float* sums   = (float*)(small + 256);
    float* scores = (float*)(small + 8192);
    float* attn   = (float*)(small + 24576);
    bf16*  wbuf   = (bf16*)(small + 40960);
    bf16* xT   = qkv2;   // alias: dead before k_dwconv writes qkv2
    bf16* outT = qkv1;   // alias: qkv1 dead after k_dwconv

    (void)hipMemsetAsync(small, 0, 40960, stream);  // flag, sums, scores, attn
    k_sniff<<<1, 256, 0, stream>>>((const uint16_t*)px, flag);
    k_cvtw<<<(WTOTAL + 255) / 256, 256, 0, stream>>>(pq, pd, pp, pt, wbuf, flag);
    k_transpose<<<dim3(6912, NB), 256, 0, stream>>>(px, xT, flag);
    k_gemm_bt<<<dim3(NSP / 128, 3, NB), 256, 0, stream>>>(
        wbuf + WOFF_QKVW, xT, qkv1, C3, nullptr);
    k_dwconv<<<dim3(NB * C3, 8), 256, 0, stream>>>(qkv1, wbuf + WOFF_DWW, qkv2, sums);
    k_scores<<<dim3(108, NH, NB), 256, 0, stream>>>(qkv2, scores);
    k_softmax<<<1, 256, 0, stream>>>(scores, sums, wbuf + WOFF_TEMP, attn);
    k_av<<<dim3(108, NH, NB), 256, 0, stream>>>(qkv2, attn, outT);
    k_gemm_bt<<<dim3(NSP / 128, 1, NB), 256, 0, stream>>>(
        wbuf + WOFF_PROJ, outT, d_out, CIN, flag);
}

// Round 4
// 555.564 us; speedup vs baseline: 2.8148x; 1.4532x over previous
//
#include <hip/hip_runtime.h>
#include <hip/hip_bf16.h>
#include <stdint.h>
#include <stddef.h>

#define NSP 110592      // 48^3
#define SD  48
#define SD2 2304        // 48*48
#define CIN 128
#define C3  384
#define NH  8
#define NB  2
#define NQ  84934656ull // NB*C3*NSP

typedef __hip_bfloat16 bf16;
typedef __bf16 bf16x8 __attribute__((ext_vector_type(8)));
typedef float  f32x4  __attribute__((ext_vector_type(4)));

// wbuf element offsets (all bf16): qkvw | dww | projw | temp
#define WOFF_QKVW 0
#define WOFF_DWW  49152
#define WOFF_PROJ 59520
#define WOFF_TEMP 75904
#define WTOTAL    75912

__device__ __forceinline__ float ldb(const bf16* p){ return __bfloat162float(*p); }
__device__ __forceinline__ float b2f(uint16_t u){
    union { float f; uint32_t i; } x; x.i = (uint32_t)u << 16; return x.f;
}
__device__ __forceinline__ uint16_t f2b(float f){
    bf16 h = __float2bfloat16(f); return *(uint16_t*)&h;
}

// ---- sniffer: flag=1 if inputs are fp32, 0 if bf16 ---------------------------
__global__ void k_sniff(const uint16_t* __restrict__ x16, int* __restrict__ flag)
{
    int t = threadIdx.x; int cnt = 0;
    for (int i = 0; i < 16; ++i) {
        uint16_t b = x16[(size_t)(t * 16 + i) * 2];   // even halves only
        int e = (b >> 7) & 0xFF;
        if (e >= 100 && e <= 140) ++cnt;              // bf16-exponent-plausible
    }
    for (int off = 32; off; off >>= 1) cnt += __shfl_down(cnt, off, 64);
    __shared__ int s[4];
    if ((t & 63) == 0) s[t >> 6] = cnt;
    __syncthreads();
    if (t == 0) *flag = (s[0] + s[1] + s[2] + s[3] < 2048) ? 1 : 0;
}

// ---- canonicalize all weights to bf16 in wbuf --------------------------------
__global__ void k_cvtw(const void* __restrict__ qw, const void* __restrict__ dw,
                       const void* __restrict__ pw, const void* __restrict__ tw,
                       bf16* __restrict__ wbuf, const int* __restrict__ flagp)
{
    int f = *flagp;
    int idx = blockIdx.x * 256 + threadIdx.x;
    if (idx >= WTOTAL) return;
    const void* src; int off;
    if (idx < WOFF_DWW)      { src = qw; off = idx; }
    else if (idx < WOFF_PROJ){ src = dw; off = idx - WOFF_DWW; }
    else if (idx < WOFF_TEMP){ src = pw; off = idx - WOFF_PROJ; }
    else                     { src = tw; off = idx - WOFF_TEMP; }
    float v = f ? ((const float*)src)[off]
                : __bfloat162float(((const bf16*)src)[off]);
    wbuf[idx] = __float2bfloat16(v);
}

// ---- K0: transpose x[b][c][n] -> xT[b][n][c] (bf16 out, dual-dtype in) -------
__global__ __launch_bounds__(256) void k_transpose(const void* __restrict__ xin,
                                                   bf16* __restrict__ xT,
                                                   const int* __restrict__ flagp)
{
    int f = *flagp;
    int b = blockIdx.y;
    size_t tid = (size_t)blockIdx.x * 256 + threadIdx.x;
    int c = (int)(tid & 127);
    size_t n8 = tid >> 7;
    size_t base = ((size_t)b * CIN + c) * NSP + n8 * 8;
    bf16 pv[8];
    if (f) {
        const float* src = (const float*)xin + base;
        float4 a = *(const float4*)src;
        float4 d = *(const float4*)(src + 4);
        pv[0] = __float2bfloat16(a.x); pv[1] = __float2bfloat16(a.y);
        pv[2] = __float2bfloat16(a.z); pv[3] = __float2bfloat16(a.w);
        pv[4] = __float2bfloat16(d.x); pv[5] = __float2bfloat16(d.y);
        pv[6] = __float2bfloat16(d.z); pv[7] = __float2bfloat16(d.w);
    } else {
        uint4 v = *(const uint4*)((const bf16*)xin + base);
        const bf16* q = (const bf16*)&v;
#pragma unroll
        for (int j = 0; j < 8; ++j) pv[j] = q[j];
    }
    bf16* dst = xT + ((size_t)b * NSP + n8 * 8) * CIN + c;
#pragma unroll
    for (int j = 0; j < 8; ++j) dst[(size_t)j * CIN] = pv[j];
}

// ---- GEMM  C[b][m][n] = A[m][k] * BT[b][n][k], K=128, 128x128 tiles ----------
// mblocks==3: bx encodes (nb,mb) with the 3 mb-variants 8 blocks apart so they
// land on the same XCD (round-robin heuristic) and share the B tile in L2.
__global__ __launch_bounds__(256) void k_gemm_bt(const bf16* __restrict__ A,
                                                 const bf16* __restrict__ BT,
                                                 void* __restrict__ Cout,
                                                 int Mtotal,
                                                 const int* __restrict__ flagp,
                                                 int mblocks)
{
    __shared__ __align__(16) bf16 lA[128 * CIN];
    __shared__ __align__(16) bf16 lB[128 * CIN];
    int b = blockIdx.z;
    int bx = blockIdx.x;
    int mb, nb;
    if (mblocks == 3) {
        int g = bx / 24, w = bx % 24;
        nb = g * 8 + (w & 7);
        mb = w >> 3;
    } else { mb = 0; nb = bx; }
    size_t nbase = (size_t)nb * 128;
    const bf16* gA = A + (size_t)mb * 128 * CIN;
    const bf16* gB = BT + ((size_t)b * NSP + nbase) * CIN;
    int t = threadIdx.x;
#pragma unroll
    for (int i = 0; i < 8; ++i) {
        int off = (i * 256 + t) * 8;
        *(uint4*)&lA[off] = *(const uint4*)&gA[off];
        *(uint4*)&lB[off] = *(const uint4*)&gB[off];
    }
    __syncthreads();

    int wave = t >> 6, lane = t & 63;
    int wm = (wave & 1) * 64, wn = (wave >> 1) * 64;
    int lr = lane & 15, lq = lane >> 4;
    f32x4 acc[4][4];
#pragma unroll
    for (int mi = 0; mi < 4; ++mi)
#pragma unroll
        for (int ni = 0; ni < 4; ++ni) acc[mi][ni] = (f32x4){0.f, 0.f, 0.f, 0.f};

#pragma unroll
    for (int ks = 0; ks < 4; ++ks) {
        int kof = ks * 32 + lq * 8;
        bf16x8 af[4], bfv[4];
#pragma unroll
        for (int mi = 0; mi < 4; ++mi)
            af[mi] = *(const bf16x8*)&lA[(wm + mi * 16 + lr) * CIN + kof];
#pragma unroll
        for (int ni = 0; ni < 4; ++ni)
            bfv[ni] = *(const bf16x8*)&lB[(wn + ni * 16 + lr) * CIN + kof];
#pragma unroll
        for (int mi = 0; mi < 4; ++mi)
#pragma unroll
            for (int ni = 0; ni < 4; ++ni)
                acc[mi][ni] = __builtin_amdgcn_mfma_f32_16x16x32_bf16(
                    af[mi], bfv[ni], acc[mi][ni], 0, 0, 0);
    }

    int f32o = flagp ? *flagp : 0;
    size_t cb = ((size_t)b * Mtotal + (size_t)mb * 128) * NSP + nbase;
    if (f32o) {
        float* Cb = (float*)Cout + cb;
#pragma unroll
        for (int mi = 0; mi < 4; ++mi)
#pragma unroll
            for (int ni = 0; ni < 4; ++ni)
#pragma unroll
                for (int r = 0; r < 4; ++r)
                    Cb[(size_t)(wm + mi * 16 + lq * 4 + r) * NSP + wn + ni * 16 + lr]
                        = acc[mi][ni][r];
    } else {
        bf16* Cb = (bf16*)Cout + cb;
#pragma unroll
        for (int mi = 0; mi < 4; ++mi)
#pragma unroll
            for (int ni = 0; ni < 4; ++ni)
#pragma unroll
                for (int r = 0; r < 4; ++r)
                    Cb[(size_t)(wm + mi * 16 + lq * 4 + r) * NSP + wn + ni * 16 + lr]
                        = __float2bfloat16(acc[mi][ni][r]);
    }
}

// ---- K2: depthwise 3x3x3 conv, LDS-tiled, 4-wide vectorized strips -----------
// grid (768, 8): block = (channel, 6-z output slab). LDS: 8 haloed input planes
// 50rows x 64cols bf16 (halo col 7 & 56). Compute: 576 strips of 4 d-columns;
// per strip-plane-row: 1 ds_read_b64 + 2 ds_read_u16 (vs 9 scalar before).
#define PLN 3200        // 64*50
__global__ __launch_bounds__(256) void k_dwconv(const bf16* __restrict__ qkv1,
                                                const bf16* __restrict__ dw,
                                                bf16* __restrict__ qkv2,
                                                float* __restrict__ sums)
{
    __shared__ __align__(16) bf16 lds[8 * PLN];
    __shared__ float red[4];
    int bc = blockIdx.x;
    int slab = blockIdx.y;
    int z0 = slab * 6;
    int ch = bc % C3;
    int t = threadIdx.x;
    const bf16* src = qkv1 + (size_t)bc * NSP;
    bf16* dst = qkv2 + (size_t)bc * NSP;

    float wgt[27];
#pragma unroll
    for (int i = 0; i < 27; ++i) wgt[i] = ldb(&dw[ch * 27 + i]);

    // phase 0: zero all of LDS
#pragma unroll
    for (int i = 0; i < 13; ++i) {
        int idx = i * 256 + t;
        if (idx < 3200) *(uint4*)&lds[idx * 8] = (uint4){0, 0, 0, 0};
    }
    __syncthreads();

    // phase 1: stage 8 planes (z0-1 .. z0+6); 288 uint4 per plane
#pragma unroll
    for (int i = 0; i < 9; ++i) {
        int vidx = i * 256 + t;            // 0..2303
        int p = vidx / 288;
        int r = vidx - p * 288;
        int y = r / 6;
        int dg = r - y * 6;
        int zp = z0 - 1 + p;
        if ((unsigned)zp < SD) {
            uint4 v = *(const uint4*)&src[(size_t)zp * SD2 + y * SD + dg * 8];
            *(uint4*)&lds[(p * PLN + (y + 1) * 64 + 8 + dg * 8)] = v;
        }
    }
    __syncthreads();

    // phase 2: strips. 576 strips: strip s -> y = s/12, d-base = (s%12)*4.
    float ssq = 0.f;
#pragma unroll 1
    for (int r = 0; r < 3; ++r) {
        int s = r * 256 + t;
        if (s < 576) {                      // wave-uniform (residual = wave 0)
            int y = s / 12;
            int c4 = (s - y * 12) * 4;
            float acc[6][4];
#pragma unroll
            for (int oz = 0; oz < 6; ++oz)
#pragma unroll
                for (int d = 0; d < 4; ++d) acc[oz][d] = 0.f;

#pragma unroll
            for (int pl = 0; pl < 8; ++pl) {
                const uint16_t* P =
                    (const uint16_t*)lds + pl * PLN + y * 64 + 8 + c4;
                float v[3][6];
#pragma unroll
                for (int dy = 0; dy < 3; ++dy) {
                    const uint16_t* R = P + dy * 64;
                    uint2 m = *(const uint2*)R;            // d..d+3 (8B aligned)
                    v[dy][0] = b2f(R[-1]);
                    v[dy][1] = b2f((uint16_t)m.x);
                    v[dy][2] = b2f((uint16_t)(m.x >> 16));
                    v[dy][3] = b2f((uint16_t)m.y);
                    v[dy][4] = b2f((uint16_t)(m.y >> 16));
                    v[dy][5] = b2f(R[4]);
                }
                float p0[4] = {0.f,0.f,0.f,0.f};
                float p1[4] = {0.f,0.f,0.f,0.f};
                float p2[4] = {0.f,0.f,0.f,0.f};
#pragma unroll
                for (int dy = 0; dy < 3; ++dy)
#pragma unroll
                    for (int dd = 0; dd < 3; ++dd) {
                        float w0 = wgt[dy * 3 + dd];
                        float w1 = wgt[9 + dy * 3 + dd];
                        float w2 = wgt[18 + dy * 3 + dd];
#pragma unroll
                        for (int d = 0; d < 4; ++d) {
                            float xv = v[dy][d + dd];
                            if (pl <= 5)            p0[d] += w0 * xv;
                            if (pl >= 1 && pl <= 6) p1[d] += w1 * xv;
                            if (pl >= 2)            p2[d] += w2 * xv;
                        }
                    }
#pragma unroll
                for (int d = 0; d < 4; ++d) {
                    if (pl <= 5)            acc[pl][d]     += p0[d];
                    if (pl >= 1 && pl <= 6) acc[pl - 1][d] += p1[d];
                    if (pl >= 2)            acc[pl - 2][d] += p2[d];
                }
            }
#pragma unroll
            for (int oz = 0; oz < 6; ++oz) {
                uint16_t u0 = f2b(acc[oz][0]), u1 = f2b(acc[oz][1]);
                uint16_t u2 = f2b(acc[oz][2]), u3 = f2b(acc[oz][3]);
                uint2 o;
                o.x = (uint32_t)u0 | ((uint32_t)u1 << 16);
                o.y = (uint32_t)u2 | ((uint32_t)u3 << 16);
                *(uint2*)&dst[(size_t)(z0 + oz) * SD2 + y * SD + c4] = o;
#pragma unroll
                for (int d = 0; d < 4; ++d) ssq += acc[oz][d] * acc[oz][d];
            }
        }
    }

    for (int off = 32; off; off >>= 1) ssq += __shfl_down(ssq, off, 64);
    if ((t & 63) == 0) red[t >> 6] = ssq;
    __syncthreads();
    if (t == 0) atomicAdd(&sums[bc], red[0] + red[1] + red[2] + red[3]);
}

// ---- K3: scores S[b][h][i][j] = sum_n q_i k_j  (MFMA, full n coverage) -------
__global__ __launch_bounds__(256) void k_scores(const bf16* __restrict__ qkv2,
                                                float* __restrict__ scores)
{
    int b = blockIdx.z, h = blockIdx.y;
    const bf16* qb = qkv2 + ((size_t)b * C3 + h * 16) * NSP;
    const bf16* kb = qkv2 + ((size_t)b * C3 + 128 + h * 16) * NSP;
    int t = threadIdx.x, w = t >> 6, lane = t & 63;
    int m = lane & 15, q4 = lane >> 4;
    size_t n0 = (size_t)blockIdx.x * 1024 + (size_t)w * 256 + (size_t)q4 * 8;
    const bf16* qp = qb + (size_t)m * NSP + n0;
    const bf16* kp = kb + (size_t)m * NSP + n0;
    f32x4 acc = (f32x4){0.f, 0.f, 0.f, 0.f};
#pragma unroll
    for (int it = 0; it < 8; ++it) {
        bf16x8 a  = *(const bf16x8*)(qp + it * 32);
        bf16x8 bb = *(const bf16x8*)(kp + it * 32);
        acc = __builtin_amdgcn_mfma_f32_16x16x32_bf16(a, bb, acc, 0, 0, 0);
    }
    float* srow = scores + (size_t)(b * NH + h) * 256;
#pragma unroll
    for (int r = 0; r < 4; ++r)
        atomicAdd(&srow[(q4 * 4 + r) * 16 + m], acc[r]);
}

// ---- K4: normalize + temperature + softmax -----------------------------------
__global__ void k_softmax(const float* __restrict__ scores,
                          const float* __restrict__ sums,
                          const bf16* __restrict__ temp,
                          float* __restrict__ attn)
{
    int t = threadIdx.x;             // t = b*128 + h*16 + i
    int h = (t >> 4) & 7, b = t >> 7;
    float tau = __bfloat162float(temp[h]);
    float invq = 1.f / fmaxf(sqrtf(sums[b * C3 + (t & 127)]), 1e-12f);
    const float* srow = scores + (size_t)t * 16;
    float s[16]; float mx = -3.4e38f;
#pragma unroll
    for (int j = 0; j < 16; ++j) {
        float invk = 1.f / fmaxf(sqrtf(sums[b * C3 + 128 + h * 16 + j]), 1e-12f);
        s[j] = srow[j] * invq * invk * tau;
        mx = fmaxf(mx, s[j]);
    }
    float sum = 0.f;
#pragma unroll
    for (int j = 0; j < 16; ++j) { s[j] = expf(s[j] - mx); sum += s[j]; }
    float inv = 1.f / sum;
    float* arow = attn + (size_t)t * 16;
#pragma unroll
    for (int j = 0; j < 16; ++j) arow[j] = s[j] * inv;
}

// ---- K5: outT[b][n][h*16+i] = sum_j attn[i][j] v[j][n] -----------------------
__global__ __launch_bounds__(256) void k_av(const bf16* __restrict__ qkv2,
                                            const float* __restrict__ attn,
                                            bf16* __restrict__ outT)
{
    int b = blockIdx.z, h = blockIdx.y;
    const bf16* vb = qkv2 + ((size_t)b * C3 + 256 + h * 16) * NSP;
    __shared__ float at[256];        // at[j*16+i]
    int t = threadIdx.x;
    {
        int i = t >> 4, j = t & 15;
        at[j * 16 + i] = attn[(size_t)(b * NH + h) * 256 + t];
    }
    __syncthreads();
    size_t n0 = (size_t)blockIdx.x * 1024 + (size_t)t * 4;
    float acc[16][4];
#pragma unroll
    for (int i = 0; i < 16; ++i)
#pragma unroll
        for (int k = 0; k < 4; ++k) acc[i][k] = 0.f;
#pragma unroll
    for (int j = 0; j < 16; ++j) {
        uint2 raw = *(const uint2*)&vb[(size_t)j * NSP + n0];
        const bf16* rp = (const bf16*)&raw;
        float vf[4];
#pragma unroll
        for (int k = 0; k < 4; ++k) vf[k] = ldb(&rp[k]);
#pragma unroll
        for (int i = 0; i < 16; ++i) {
            float wv = at[j * 16 + i];
#pragma unroll
            for (int k = 0; k < 4; ++k) acc[i][k] += wv * vf[k];
        }
    }
    bf16* ob = outT + ((size_t)b * NSP + n0) * CIN + h * 16;
#pragma unroll
    for (int k = 0; k < 4; ++k) {
        bf16 tmp[16];
#pragma unroll
        for (int i = 0; i < 16; ++i) tmp[i] = __float2bfloat16(acc[i][k]);
        *(uint4*)&ob[(size_t)k * CIN]     = *(uint4*)&tmp[0];
        *(uint4*)&ob[(size_t)k * CIN + 8] = *(uint4*)&tmp[8];
    }
}

// ---- host --------------------------------------------------------------------
extern "C" void kernel_launch(void* const* d_in, const int* in_sizes, int n_in,
                              void* d_out, int out_size, void* d_ws, size_t ws_size,
                              hipStream_t stream)
{
    const void *px = nullptr, *pq = nullptr, *pd = nullptr, *pp = nullptr, *pt = nullptr;
    for (int i = 0; i < n_in; ++i) {
        switch (in_sizes[i]) {
            case 28311552: px = d_in[i]; break;   // x
            case 49152:    pq = d_in[i]; break;   // qkv_w
            case 10368:    pd = d_in[i]; break;   // dw_w
            case 16384:    pp = d_in[i]; break;   // proj_w
            case 8:        pt = d_in[i]; break;   // temperature
        }
    }
    const size_t required = NQ * 4 + (1u << 20);
    if (!px || !pq || !pd || !pp || !pt || ws_size < required) {
        (void)hipMemsetAsync(d_out, 0, (size_t)out_size * 2, stream);
        return;
    }

    char* ws = (char*)d_ws;
    bf16* qkv1 = (bf16*)ws;                       // NQ bf16
    bf16* qkv2 = (bf16*)(ws + NQ * 2);            // NQ bf16
    char* small = ws + NQ * 4;
    int*   flag   = (int*)small;
    float* sums   = (float*)(small + 256);
    float* scores = (float*)(small + 8192);
    float* attn   = (float*)(small + 24576);
    bf16*  wbuf   = (bf16*)(small + 40960);
    bf16* xT   = qkv2;   // alias: dead before k_dwconv writes qkv2
    bf16* outT = qkv1;   // alias: qkv1 dead after k_dwconv

    (void)hipMemsetAsync(small, 0, 40960, stream);  // flag, sums, scores, attn
    k_sniff<<<1, 256, 0, stream>>>((const uint16_t*)px, flag);
    k_cvtw<<<(WTOTAL + 255) / 256, 256, 0, stream>>>(pq, pd, pp, pt, wbuf, flag);
    k_transpose<<<dim3(6912, NB), 256, 0, stream>>>(px, xT, flag);
    k_gemm_bt<<<dim3(864 * 3, 1, NB), 256, 0, stream>>>(
        wbuf + WOFF_QKVW, xT, qkv1, C3, nullptr, 3);
    k_dwconv<<<dim3(NB * C3, 8), 256, 0, stream>>>(qkv1, wbuf + WOFF_DWW, qkv2, sums);
    k_scores<<<dim3(108, NH, NB), 256, 0, stream>>>(qkv2, scores);
    k_softmax<<<1, 256, 0, stream>>>(scores, sums, wbuf + WOFF_TEMP, attn);
    k_av<<<dim3(108, NH, NB), 256, 0, stream>>>(qkv2, attn, outT);
    k_gemm_bt<<<dim3(864, 1, NB), 256, 0, stream>>>(
        wbuf + WOFF_PROJ, outT, d_out, CIN, flag, 1);
}